// Round 1
// baseline (1419.963 us; speedup 1.0000x reference)
//
#include <hip/hip_runtime.h>

#define NN 100000
#define NE 1600000
#define IN_DIM 16
#define MSG_DIM 128
#define DT_C 0.1f
#define EPS_C 1e-8f

// Wc[i][j] = sum_k W_msg[i][k] * W_out[k][j]   (16x16)
// bc[j]    = sum_k b_msg[k]    * W_out[k][j]   (16)
__global__ void compute_wc_kernel(const float* __restrict__ W_msg,
                                  const float* __restrict__ b_msg,
                                  const float* __restrict__ W_out,
                                  float* __restrict__ Wc,
                                  float* __restrict__ bc) {
    int t = threadIdx.x;            // 256 threads
    int i = t >> 4, j = t & 15;
    float s = 0.f;
    for (int k = 0; k < MSG_DIM; ++k)
        s += W_msg[i * MSG_DIM + k] * W_out[k * IN_DIM + j];
    Wc[t] = s;
    if (t < IN_DIM) {
        float sb = 0.f;
        for (int k = 0; k < MSG_DIM; ++k)
            sb += b_msg[k] * W_out[k * IN_DIM + t];
        bc[t] = sb;
    }
}

__global__ void deg_kernel(const int* __restrict__ dst, float* __restrict__ deg) {
    int e = blockIdx.x * blockDim.x + threadIdx.x;
    if (e < NE) atomicAdd(&deg[dst[e]], 1.0f);
}

// 4 threads per edge; each moves one float4 of x[src] into agg[dst] via atomics.
__global__ void scatter_kernel(const float4* __restrict__ x4,
                               const int* __restrict__ src,
                               const int* __restrict__ dst,
                               float* __restrict__ agg) {
    long long tid = (long long)blockIdx.x * blockDim.x + threadIdx.x;
    int e = (int)(tid >> 2);
    int q = (int)(tid & 3);
    if (e >= NE) return;
    int s = src[e];
    int d = dst[e];
    float4 v = x4[s * 4 + q];
    float* a = agg + (size_t)d * IN_DIM + q * 4;
    atomicAdd(a + 0, v.x);
    atomicAdd(a + 1, v.y);
    atomicAdd(a + 2, v.z);
    atomicAdd(a + 3, v.w);
}

// Per-node: out = agg @ Wc + deg*bc + b_out ; x += DT*out ; renorm cols 3..6.
// Safe in place (each thread touches only its own row).
__global__ void update_kernel(const float* __restrict__ xin,
                              const float* __restrict__ agg,
                              const float* __restrict__ deg,
                              const float* __restrict__ Wc,
                              const float* __restrict__ bc,
                              const float* __restrict__ b_out,
                              float* __restrict__ xout) {
    __shared__ float sWc[256];
    __shared__ float sbc[16];
    __shared__ float sb[16];
    int t = threadIdx.x;
    sWc[t] = Wc[t];
    if (t < 16) { sbc[t] = bc[t]; sb[t] = b_out[t]; }
    __syncthreads();

    int n = blockIdx.x * blockDim.x + t;
    if (n >= NN) return;

    float a[16], xv[16];
    const float4* ap = (const float4*)(agg + (size_t)n * IN_DIM);
    const float4* xp = (const float4*)(xin + (size_t)n * IN_DIM);
    #pragma unroll
    for (int q = 0; q < 4; ++q) {
        float4 av = ap[q];
        a[q * 4 + 0] = av.x; a[q * 4 + 1] = av.y; a[q * 4 + 2] = av.z; a[q * 4 + 3] = av.w;
        float4 xvv = xp[q];
        xv[q * 4 + 0] = xvv.x; xv[q * 4 + 1] = xvv.y; xv[q * 4 + 2] = xvv.z; xv[q * 4 + 3] = xvv.w;
    }
    float dg = deg[n];

    float o[16];
    #pragma unroll
    for (int j = 0; j < 16; ++j) o[j] = dg * sbc[j] + sb[j];
    #pragma unroll
    for (int k = 0; k < 16; ++k) {
        float ak = a[k];
        #pragma unroll
        for (int j = 0; j < 16; ++j) o[j] = fmaf(ak, sWc[k * 16 + j], o[j]);
    }

    float xn[16];
    #pragma unroll
    for (int j = 0; j < 16; ++j) xn[j] = xv[j] + DT_C * o[j];

    float ss = xn[3] * xn[3] + xn[4] * xn[4] + xn[5] * xn[5] + xn[6] * xn[6];
    float nrm = sqrtf(ss);
    float sc = 1.0f / fmaxf(nrm, EPS_C);
    xn[3] *= sc; xn[4] *= sc; xn[5] *= sc; xn[6] *= sc;

    float4* op = (float4*)(xout + (size_t)n * IN_DIM);
    #pragma unroll
    for (int q = 0; q < 4; ++q) {
        float4 v;
        v.x = xn[q * 4 + 0]; v.y = xn[q * 4 + 1]; v.z = xn[q * 4 + 2]; v.w = xn[q * 4 + 3];
        op[q] = v;
    }
}

extern "C" void kernel_launch(void* const* d_in, const int* in_sizes, int n_in,
                              void* d_out, int out_size, void* d_ws, size_t ws_size,
                              hipStream_t stream) {
    const float* x0    = (const float*)d_in[0];
    const int*   ei    = (const int*)d_in[1];   // (2, NE) int32: row0=src, row1=dst
    const float* W_msg = (const float*)d_in[2];
    const float* b_msg = (const float*)d_in[3];
    const float* W_out = (const float*)d_in[4];
    const float* b_out = (const float*)d_in[5];
    // d_in[6] = steps (always 4 per setup_inputs)

    float* X = (float*)d_out;                   // evolving node state, 100K x 16

    char* ws = (char*)d_ws;
    float* agg = (float*)ws;                        // NN*16 floats = 6.4 MB
    float* deg = agg + (size_t)NN * IN_DIM;         // NN floats
    float* Wc  = deg + NN;                          // 256 floats
    float* bc  = Wc + 256;                          // 16 floats

    const int* src = ei;
    const int* dst = ei + NE;

    compute_wc_kernel<<<1, 256, 0, stream>>>(W_msg, b_msg, W_out, Wc, bc);
    hipMemsetAsync(deg, 0, (size_t)NN * sizeof(float), stream);
    deg_kernel<<<(NE + 255) / 256, 256, 0, stream>>>(dst, deg);

    const int scatter_threads = NE * 4;
    for (int s = 0; s < 4; ++s) {
        const float* xin = (s == 0) ? x0 : X;
        hipMemsetAsync(agg, 0, (size_t)NN * IN_DIM * sizeof(float), stream);
        scatter_kernel<<<(scatter_threads + 255) / 256, 256, 0, stream>>>(
            (const float4*)xin, src, dst, agg);
        update_kernel<<<(NN + 255) / 256, 256, 0, stream>>>(
            xin, agg, deg, Wc, bc, b_out, X);
    }
}

// Round 3
// 529.543 us; speedup vs baseline: 2.6815x; 2.6815x over previous
//
#include <hip/hip_runtime.h>

#define NN 100000
#define NE 1600000
#define IN_DIM 16
#define MSG_DIM 128
#define DT_C 0.1f
#define EPS_C 1e-8f
#define SCAN_T 1024
#define CHUNK ((NN + SCAN_T - 1) / SCAN_T)   // 98

// Wc = W_msg @ W_out (16x16), bc = b_msg @ W_out (16)
__global__ void compute_wc_kernel(const float* __restrict__ W_msg,
                                  const float* __restrict__ b_msg,
                                  const float* __restrict__ W_out,
                                  float* __restrict__ Wc,
                                  float* __restrict__ bc) {
    int t = threadIdx.x;            // 256 threads
    int i = t >> 4, j = t & 15;
    float s = 0.f;
    for (int k = 0; k < MSG_DIM; ++k)
        s += W_msg[i * MSG_DIM + k] * W_out[k * IN_DIM + j];
    Wc[t] = s;
    if (t < IN_DIM) {
        float sb = 0.f;
        for (int k = 0; k < MSG_DIM; ++k)
            sb += b_msg[k] * W_out[k * IN_DIM + t];
        bc[t] = sb;
    }
}

__global__ void hist_kernel(const int* __restrict__ dst, int* __restrict__ cnt) {
    int e = blockIdx.x * blockDim.x + threadIdx.x;
    if (e < NE) atomicAdd(&cnt[dst[e]], 1);
}

// Single-block exclusive scan of cnt -> offs; zeroes cnt for reuse as cursor.
__global__ __launch_bounds__(SCAN_T) void scan_kernel(int* __restrict__ cnt,
                                                      int* __restrict__ offs) {
    __shared__ int part[SCAN_T];
    int t = threadIdx.x;
    int b = t * CHUNK;
    int e = min(b + CHUNK, NN);
    int s = 0;
    for (int i = b; i < e; ++i) s += cnt[i];
    part[t] = s;
    __syncthreads();
    for (int off = 1; off < SCAN_T; off <<= 1) {
        int v = (t >= off) ? part[t - off] : 0;
        __syncthreads();
        part[t] += v;
        __syncthreads();
    }
    int base = (t == 0) ? 0 : part[t - 1];
    for (int i = b; i < e; ++i) {
        int c = cnt[i];
        offs[i] = base;
        base += c;
        cnt[i] = 0;                 // becomes the fill cursor
    }
    if (t == SCAN_T - 1) offs[NN] = part[SCAN_T - 1];
}

__global__ void fill_kernel(const int* __restrict__ src,
                            const int* __restrict__ dst,
                            const int* __restrict__ offs,
                            int* __restrict__ cur,
                            int* __restrict__ csr) {
    int e = blockIdx.x * blockDim.x + threadIdx.x;
    if (e >= NE) return;
    int d = dst[e];
    int p = atomicAdd(&cur[d], 1);
    csr[offs[d] + p] = src[e];
}

// Fused per-step kernel: 4 threads per node (q = quarter of the 16-dim row).
// gather-sum x[src] over incoming edges -> exchange quarters via shfl ->
// 16x16 matvec -> Euler update -> pol renorm -> store.
// NOTE: xin and xout MUST be different buffers (gather reads neighbor rows).
__global__ __launch_bounds__(256) void step_kernel(const float4* __restrict__ x4in,
                                                   const int* __restrict__ offs,
                                                   const int* __restrict__ csr,
                                                   const float* __restrict__ Wc,
                                                   const float* __restrict__ bc,
                                                   const float* __restrict__ b_out,
                                                   float4* __restrict__ x4out) {
    __shared__ float sWc[256];
    __shared__ float sbc[16];
    __shared__ float sb[16];
    int t = threadIdx.x;
    sWc[t] = Wc[t];
    if (t < 16) { sbc[t] = bc[t]; sb[t] = b_out[t]; }
    __syncthreads();

    int tid = blockIdx.x * 256 + t;
    int n = tid >> 2;
    int q = tid & 3;
    if (n >= NN) return;

    int o0 = offs[n];
    int o1 = offs[n + 1];

    float4 acc = make_float4(0.f, 0.f, 0.f, 0.f);
    for (int e = o0; e < o1; ++e) {
        int s = csr[e];
        float4 v = x4in[s * 4 + q];
        acc.x += v.x; acc.y += v.y; acc.z += v.z; acc.w += v.w;
    }

    // assemble full 16-dim aggregate across the 4-lane group
    float a[16];
    a[4 * q + 0] = acc.x; a[4 * q + 1] = acc.y; a[4 * q + 2] = acc.z; a[4 * q + 3] = acc.w;
    #pragma unroll
    for (int m = 1; m < 4; ++m) {
        int p = q ^ m;
        a[4 * p + 0] = __shfl_xor(acc.x, m);
        a[4 * p + 1] = __shfl_xor(acc.y, m);
        a[4 * p + 2] = __shfl_xor(acc.z, m);
        a[4 * p + 3] = __shfl_xor(acc.w, m);
    }

    float dg = (float)(o1 - o0);

    // this lane's 4 output columns j = 4q..4q+3
    float o[4];
    #pragma unroll
    for (int jj = 0; jj < 4; ++jj) {
        int j = 4 * q + jj;
        float s = dg * sbc[j] + sb[j];
        #pragma unroll
        for (int k = 0; k < 16; ++k)
            s = fmaf(a[k], sWc[k * 16 + j], s);
        o[jj] = s;
    }

    float4 xv = x4in[(size_t)n * 4 + q];
    float xn[4];
    xn[0] = xv.x + DT_C * o[0];
    xn[1] = xv.y + DT_C * o[1];
    xn[2] = xv.z + DT_C * o[2];
    xn[3] = xv.w + DT_C * o[3];

    // pol columns 3..6: q==0 holds col 3 (xn[3]); q==1 holds cols 4,5,6 (xn[0..2])
    float ssp = 0.f;
    if (q == 0) ssp = xn[3] * xn[3];
    if (q == 1) ssp = xn[0] * xn[0] + xn[1] * xn[1] + xn[2] * xn[2];
    ssp += __shfl_xor(ssp, 1);
    ssp += __shfl_xor(ssp, 2);
    float sc = 1.0f / fmaxf(sqrtf(ssp), EPS_C);
    if (q == 0) xn[3] *= sc;
    if (q == 1) { xn[0] *= sc; xn[1] *= sc; xn[2] *= sc; }

    float4 outv = make_float4(xn[0], xn[1], xn[2], xn[3]);
    x4out[(size_t)n * 4 + q] = outv;
}

extern "C" void kernel_launch(void* const* d_in, const int* in_sizes, int n_in,
                              void* d_out, int out_size, void* d_ws, size_t ws_size,
                              hipStream_t stream) {
    const float* x0    = (const float*)d_in[0];
    const int*   ei    = (const int*)d_in[1];   // (2, NE): row0=src, row1=dst
    const float* W_msg = (const float*)d_in[2];
    const float* b_msg = (const float*)d_in[3];
    const float* W_out = (const float*)d_in[4];
    const float* b_out = (const float*)d_in[5];

    float* X = (float*)d_out;                   // final state buffer (ping-pong B1)

    // ws layout: Y (NN*16 f, 16B-aligned at base), cnt (NN), offs (NN+1), csr (NE), Wc, bc
    float* Y    = (float*)d_ws;                 // ping-pong B0, 6.4 MB
    int*   cnt  = (int*)(Y + (size_t)NN * IN_DIM);
    int*   offs = cnt + NN;
    int*   csr  = offs + NN + 1;
    float* Wc   = (float*)(csr + NE);
    float* bc   = Wc + 256;

    const int* src = ei;
    const int* dst = ei + NE;

    compute_wc_kernel<<<1, 256, 0, stream>>>(W_msg, b_msg, W_out, Wc, bc);
    hipMemsetAsync(cnt, 0, (size_t)NN * sizeof(int), stream);
    hist_kernel<<<(NE + 255) / 256, 256, 0, stream>>>(dst, cnt);
    scan_kernel<<<1, SCAN_T, 0, stream>>>(cnt, offs);
    fill_kernel<<<(NE + 255) / 256, 256, 0, stream>>>(src, dst, offs, cnt, csr);

    const int step_threads = NN * 4;
    const int step_blocks = (step_threads + 255) / 256;

    // 4 steps, ping-pong: x0 -> Y -> X -> Y -> X (final lands in d_out)
    const float* bufs_in[4]  = { x0, Y, X, Y };
    float*       bufs_out[4] = { Y,  X, Y, X };
    for (int s = 0; s < 4; ++s) {
        step_kernel<<<step_blocks, 256, 0, stream>>>(
            (const float4*)bufs_in[s], offs, csr, Wc, bc, b_out,
            (float4*)bufs_out[s]);
    }
}

// Round 4
// 317.809 us; speedup vs baseline: 4.4680x; 1.6662x over previous
//
#include <hip/hip_runtime.h>

#define NN 100000
#define NE 1600000
#define IN_DIM 16
#define MSG_DIM 128
#define DT_C 0.1f
#define EPS_C 1e-8f
#define NSB ((NN + 255) / 256)          // 391 scan blocks

// Wc = W_msg @ W_out (16x16), bc = b_msg @ W_out (16)
__global__ void compute_wc_kernel(const float* __restrict__ W_msg,
                                  const float* __restrict__ b_msg,
                                  const float* __restrict__ W_out,
                                  float* __restrict__ Wc,
                                  float* __restrict__ bc) {
    int t = threadIdx.x;            // 256 threads
    int i = t >> 4, j = t & 15;
    float s = 0.f;
    for (int k = 0; k < MSG_DIM; ++k)
        s += W_msg[i * MSG_DIM + k] * W_out[k * IN_DIM + j];
    Wc[t] = s;
    if (t < IN_DIM) {
        float sb = 0.f;
        for (int k = 0; k < MSG_DIM; ++k)
            sb += b_msg[k] * W_out[k * IN_DIM + t];
        bc[t] = sb;
    }
}

__global__ void hist_kernel(const int* __restrict__ dst, int* __restrict__ cnt) {
    int e = blockIdx.x * blockDim.x + threadIdx.x;
    if (e < NE) atomicAdd(&cnt[dst[e]], 1);
}

// Phase 1: per-block exclusive scan of 256-count chunk + block sum; zero cnt.
__global__ __launch_bounds__(256) void scan1_kernel(int* __restrict__ cnt,
                                                    int* __restrict__ offs,
                                                    int* __restrict__ bsum) {
    __shared__ int sh[256];
    int t = threadIdx.x;
    int i = blockIdx.x * 256 + t;
    int v = (i < NN) ? cnt[i] : 0;
    sh[t] = v;
    __syncthreads();
    #pragma unroll
    for (int off = 1; off < 256; off <<= 1) {
        int u = (t >= off) ? sh[t - off] : 0;
        __syncthreads();
        sh[t] += u;
        __syncthreads();
    }
    if (i < NN) {
        offs[i] = sh[t] - v;        // exclusive, chunk-local
        cnt[i] = 0;                 // becomes the fill cursor
    }
    if (t == 255) bsum[blockIdx.x] = sh[255];
}

// Phase 2: single block scans the NSB block sums (exclusive), sets offs[NN].
__global__ __launch_bounds__(512) void scan2_kernel(int* __restrict__ bsum,
                                                    int* __restrict__ offs) {
    __shared__ int sh[512];
    int t = threadIdx.x;
    int v = (t < NSB) ? bsum[t] : 0;
    sh[t] = v;
    __syncthreads();
    #pragma unroll
    for (int off = 1; off < 512; off <<= 1) {
        int u = (t >= off) ? sh[t - off] : 0;
        __syncthreads();
        sh[t] += u;
        __syncthreads();
    }
    if (t < NSB) bsum[t] = sh[t] - v;   // exclusive
    if (t == 0) offs[NN] = NE;
}

// Phase 3: add block offsets.
__global__ __launch_bounds__(256) void scan3_kernel(const int* __restrict__ bsum,
                                                    int* __restrict__ offs) {
    int i = blockIdx.x * 256 + threadIdx.x;
    if (i < NN) offs[i] += bsum[blockIdx.x];
}

__global__ void fill_kernel(const int* __restrict__ src,
                            const int* __restrict__ dst,
                            const int* __restrict__ offs,
                            int* __restrict__ cur,
                            int* __restrict__ csr) {
    int e = blockIdx.x * blockDim.x + threadIdx.x;
    if (e >= NE) return;
    int d = dst[e];
    int p = atomicAdd(&cur[d], 1);
    csr[offs[d] + p] = src[e];
}

// Fused per-step kernel: 4 threads per node (q = quarter of the 16-dim row).
// gather-sum x[src] over incoming edges -> exchange quarters via shfl ->
// 16x16 matvec -> Euler update -> pol renorm -> store.
// NOTE: xin and xout MUST be different buffers (gather reads neighbor rows).
__global__ __launch_bounds__(256) void step_kernel(const float4* __restrict__ x4in,
                                                   const int* __restrict__ offs,
                                                   const int* __restrict__ csr,
                                                   const float* __restrict__ Wc,
                                                   const float* __restrict__ bc,
                                                   const float* __restrict__ b_out,
                                                   float4* __restrict__ x4out) {
    __shared__ float sWc[256];
    __shared__ float sbc[16];
    __shared__ float sb[16];
    int t = threadIdx.x;
    sWc[t] = Wc[t];
    if (t < 16) { sbc[t] = bc[t]; sb[t] = b_out[t]; }
    __syncthreads();

    int tid = blockIdx.x * 256 + t;
    int n = tid >> 2;
    int q = tid & 3;
    if (n >= NN) return;

    int o0 = offs[n];
    int o1 = offs[n + 1];

    float4 acc = make_float4(0.f, 0.f, 0.f, 0.f);
    for (int e = o0; e < o1; ++e) {
        int s = csr[e];
        float4 v = x4in[s * 4 + q];
        acc.x += v.x; acc.y += v.y; acc.z += v.z; acc.w += v.w;
    }

    // assemble full 16-dim aggregate across the 4-lane group
    float a[16];
    a[4 * q + 0] = acc.x; a[4 * q + 1] = acc.y; a[4 * q + 2] = acc.z; a[4 * q + 3] = acc.w;
    #pragma unroll
    for (int m = 1; m < 4; ++m) {
        int p = q ^ m;
        a[4 * p + 0] = __shfl_xor(acc.x, m);
        a[4 * p + 1] = __shfl_xor(acc.y, m);
        a[4 * p + 2] = __shfl_xor(acc.z, m);
        a[4 * p + 3] = __shfl_xor(acc.w, m);
    }

    float dg = (float)(o1 - o0);

    // this lane's 4 output columns j = 4q..4q+3
    float o[4];
    #pragma unroll
    for (int jj = 0; jj < 4; ++jj) {
        int j = 4 * q + jj;
        float s = dg * sbc[j] + sb[j];
        #pragma unroll
        for (int k = 0; k < 16; ++k)
            s = fmaf(a[k], sWc[k * 16 + j], s);
        o[jj] = s;
    }

    float4 xv = x4in[(size_t)n * 4 + q];
    float xn[4];
    xn[0] = xv.x + DT_C * o[0];
    xn[1] = xv.y + DT_C * o[1];
    xn[2] = xv.z + DT_C * o[2];
    xn[3] = xv.w + DT_C * o[3];

    // pol columns 3..6: q==0 holds col 3 (xn[3]); q==1 holds cols 4,5,6 (xn[0..2])
    float ssp = 0.f;
    if (q == 0) ssp = xn[3] * xn[3];
    if (q == 1) ssp = xn[0] * xn[0] + xn[1] * xn[1] + xn[2] * xn[2];
    ssp += __shfl_xor(ssp, 1);
    ssp += __shfl_xor(ssp, 2);
    float sc = 1.0f / fmaxf(sqrtf(ssp), EPS_C);
    if (q == 0) xn[3] *= sc;
    if (q == 1) { xn[0] *= sc; xn[1] *= sc; xn[2] *= sc; }

    float4 outv = make_float4(xn[0], xn[1], xn[2], xn[3]);
    x4out[(size_t)n * 4 + q] = outv;
}

extern "C" void kernel_launch(void* const* d_in, const int* in_sizes, int n_in,
                              void* d_out, int out_size, void* d_ws, size_t ws_size,
                              hipStream_t stream) {
    const float* x0    = (const float*)d_in[0];
    const int*   ei    = (const int*)d_in[1];   // (2, NE): row0=src, row1=dst
    const float* W_msg = (const float*)d_in[2];
    const float* b_msg = (const float*)d_in[3];
    const float* W_out = (const float*)d_in[4];
    const float* b_out = (const float*)d_in[5];

    float* X = (float*)d_out;                   // final state buffer (ping-pong B1)

    // ws layout: Y (NN*16 f), cnt (NN), offs (NN+1), bsum (NSB), csr (NE), Wc, bc
    float* Y    = (float*)d_ws;                 // ping-pong B0, 6.4 MB
    int*   cnt  = (int*)(Y + (size_t)NN * IN_DIM);
    int*   offs = cnt + NN;
    int*   bsum = offs + NN + 1;
    int*   csr  = bsum + NSB + 1;
    float* Wc   = (float*)(csr + NE);
    float* bc   = Wc + 256;

    const int* src = ei;
    const int* dst = ei + NE;

    compute_wc_kernel<<<1, 256, 0, stream>>>(W_msg, b_msg, W_out, Wc, bc);
    hipMemsetAsync(cnt, 0, (size_t)NN * sizeof(int), stream);
    hist_kernel<<<(NE + 255) / 256, 256, 0, stream>>>(dst, cnt);
    scan1_kernel<<<NSB, 256, 0, stream>>>(cnt, offs, bsum);
    scan2_kernel<<<1, 512, 0, stream>>>(bsum, offs);
    scan3_kernel<<<NSB, 256, 0, stream>>>(bsum, offs);
    fill_kernel<<<(NE + 255) / 256, 256, 0, stream>>>(src, dst, offs, cnt, csr);

    const int step_threads = NN * 4;
    const int step_blocks = (step_threads + 255) / 256;

    // 4 steps, ping-pong: x0 -> Y -> X -> Y -> X (final lands in d_out)
    const float* bufs_in[4]  = { x0, Y, X, Y };
    float*       bufs_out[4] = { Y,  X, Y, X };
    for (int s = 0; s < 4; ++s) {
        step_kernel<<<step_blocks, 256, 0, stream>>>(
            (const float4*)bufs_in[s], offs, csr, Wc, bc, b_out,
            (float4*)bufs_out[s]);
    }
}

// Round 5
// 288.951 us; speedup vs baseline: 4.9142x; 1.0999x over previous
//
#include <hip/hip_runtime.h>

#define NN 100000
#define NE 1600000
#define IN_DIM 16
#define MSG_DIM 128
#define DT_C 0.1f
#define EPS_C 1e-8f
#define NSB ((NN + 255) / 256)          // 391 scan blocks
#define NOCT 8
#define OCT_NODES (NN / NOCT)           // 12500
#define NCHUNK 256
#define CHUNK_E (NE / NCHUNK)           // 6250

// Wc = W_msg @ W_out (16x16), bc = b_msg @ W_out (16)
__global__ void compute_wc_kernel(const float* __restrict__ W_msg,
                                  const float* __restrict__ b_msg,
                                  const float* __restrict__ W_out,
                                  float* __restrict__ Wc,
                                  float* __restrict__ bc) {
    int t = threadIdx.x;            // 256 threads
    int i = t >> 4, j = t & 15;
    float s = 0.f;
    for (int k = 0; k < MSG_DIM; ++k)
        s += W_msg[i * MSG_DIM + k] * W_out[k * IN_DIM + j];
    Wc[t] = s;
    if (t < IN_DIM) {
        float sb = 0.f;
        for (int k = 0; k < MSG_DIM; ++k)
            sb += b_msg[k] * W_out[k * IN_DIM + t];
        bc[t] = sb;
    }
}

__global__ void hist_kernel(const int* __restrict__ dst, int* __restrict__ cnt) {
    int e = blockIdx.x * blockDim.x + threadIdx.x;
    if (e < NE) atomicAdd(&cnt[dst[e]], 1);
}

// Phase 1: per-block exclusive scan of 256-count chunk + block sum; zero cnt.
__global__ __launch_bounds__(256) void scan1_kernel(int* __restrict__ cnt,
                                                    int* __restrict__ offs,
                                                    int* __restrict__ bsum) {
    __shared__ int sh[256];
    int t = threadIdx.x;
    int i = blockIdx.x * 256 + t;
    int v = (i < NN) ? cnt[i] : 0;
    sh[t] = v;
    __syncthreads();
    #pragma unroll
    for (int off = 1; off < 256; off <<= 1) {
        int u = (t >= off) ? sh[t - off] : 0;
        __syncthreads();
        sh[t] += u;
        __syncthreads();
    }
    if (i < NN) {
        offs[i] = sh[t] - v;        // exclusive, chunk-local
        cnt[i] = 0;                 // becomes the fill cursor
    }
    if (t == 255) bsum[blockIdx.x] = sh[255];
}

// Phase 2: single block scans the NSB block sums (exclusive), sets offs[NN].
__global__ __launch_bounds__(512) void scan2_kernel(int* __restrict__ bsum,
                                                    int* __restrict__ offs) {
    __shared__ int sh[512];
    int t = threadIdx.x;
    int v = (t < NSB) ? bsum[t] : 0;
    sh[t] = v;
    __syncthreads();
    #pragma unroll
    for (int off = 1; off < 512; off <<= 1) {
        int u = (t >= off) ? sh[t - off] : 0;
        __syncthreads();
        sh[t] += u;
        __syncthreads();
    }
    if (t < NSB) bsum[t] = sh[t] - v;   // exclusive
    if (t == 0) offs[NN] = NE;
}

// Phase 3: add block offsets.
__global__ __launch_bounds__(256) void scan3_kernel(const int* __restrict__ bsum,
                                                    int* __restrict__ offs) {
    int i = blockIdx.x * 256 + threadIdx.x;
    if (i < NN) offs[i] += bsum[blockIdx.x];
}

// XCD-affine fill: block (chunk c, octant o) scans edge chunk c, handles only
// edges whose dst lies in octant o. blockIdx%8 round-robins across XCDs, so
// each octant's csr slice (~800KB) is written by one XCD's L2 -> full-line
// writebacks instead of 1 line per 4B store. Correct regardless of mapping.
__global__ __launch_bounds__(256) void fill_oct_kernel(const int* __restrict__ src,
                                                       const int* __restrict__ dst,
                                                       const int* __restrict__ offs,
                                                       int* __restrict__ cur,
                                                       int* __restrict__ csr) {
    int o = blockIdx.x & 7;
    int c = blockIdx.x >> 3;
    int base = c * CHUNK_E;
    int lo = o * OCT_NODES;
    for (int i = threadIdx.x; i < CHUNK_E; i += 256) {
        int e = base + i;
        int d = dst[e];
        if ((unsigned)(d - lo) < (unsigned)OCT_NODES) {
            int p = atomicAdd(&cur[d], 1);
            csr[offs[d] + p] = src[e];
        }
    }
}

// Fused per-step kernel: 8 threads per node. h = half (alternating edges),
// q = quarter of the 16-dim row. gather-sum -> merge halves (shfl 4) ->
// exchange quarters (shfl 1..3) -> 16x16 matvec -> Euler -> renorm -> store.
// NOTE: xin and xout MUST be different buffers (gather reads neighbor rows).
__global__ __launch_bounds__(256) void step_kernel(const float4* __restrict__ x4in,
                                                   const int* __restrict__ offs,
                                                   const int* __restrict__ csr,
                                                   const float* __restrict__ Wc,
                                                   const float* __restrict__ bc,
                                                   const float* __restrict__ b_out,
                                                   float4* __restrict__ x4out) {
    __shared__ float sWc[256];
    __shared__ float sbc[16];
    __shared__ float sb[16];
    int t = threadIdx.x;
    sWc[t] = Wc[t];
    if (t < 16) { sbc[t] = bc[t]; sb[t] = b_out[t]; }
    __syncthreads();

    int tid = blockIdx.x * 256 + t;
    int n = tid >> 3;
    int h = (tid >> 2) & 1;
    int q = tid & 3;
    if (n >= NN) return;

    int o0 = offs[n];
    int o1 = offs[n + 1];

    float4 acc = make_float4(0.f, 0.f, 0.f, 0.f);
    for (int e = o0 + h; e < o1; e += 2) {
        int s = csr[e];
        float4 v = x4in[s * 4 + q];
        acc.x += v.x; acc.y += v.y; acc.z += v.z; acc.w += v.w;
    }
    // merge the two halves (lanes differing in bit 2)
    acc.x += __shfl_xor(acc.x, 4);
    acc.y += __shfl_xor(acc.y, 4);
    acc.z += __shfl_xor(acc.z, 4);
    acc.w += __shfl_xor(acc.w, 4);

    // assemble full 16-dim aggregate across the 4-lane q-group
    float a[16];
    a[4 * q + 0] = acc.x; a[4 * q + 1] = acc.y; a[4 * q + 2] = acc.z; a[4 * q + 3] = acc.w;
    #pragma unroll
    for (int m = 1; m < 4; ++m) {
        int p = q ^ m;
        a[4 * p + 0] = __shfl_xor(acc.x, m);
        a[4 * p + 1] = __shfl_xor(acc.y, m);
        a[4 * p + 2] = __shfl_xor(acc.z, m);
        a[4 * p + 3] = __shfl_xor(acc.w, m);
    }

    float dg = (float)(o1 - o0);

    // this lane's 4 output columns j = 4q..4q+3 (computed redundantly by both halves)
    float o[4];
    #pragma unroll
    for (int jj = 0; jj < 4; ++jj) {
        int j = 4 * q + jj;
        float s = dg * sbc[j] + sb[j];
        #pragma unroll
        for (int k = 0; k < 16; ++k)
            s = fmaf(a[k], sWc[k * 16 + j], s);
        o[jj] = s;
    }

    float4 xv = x4in[(size_t)n * 4 + q];
    float xn[4];
    xn[0] = xv.x + DT_C * o[0];
    xn[1] = xv.y + DT_C * o[1];
    xn[2] = xv.z + DT_C * o[2];
    xn[3] = xv.w + DT_C * o[3];

    // pol columns 3..6: q==0 holds col 3 (xn[3]); q==1 holds cols 4,5,6 (xn[0..2])
    float ssp = 0.f;
    if (q == 0) ssp = xn[3] * xn[3];
    if (q == 1) ssp = xn[0] * xn[0] + xn[1] * xn[1] + xn[2] * xn[2];
    ssp += __shfl_xor(ssp, 1);
    ssp += __shfl_xor(ssp, 2);
    float sc = 1.0f / fmaxf(sqrtf(ssp), EPS_C);
    if (q == 0) xn[3] *= sc;
    if (q == 1) { xn[0] *= sc; xn[1] *= sc; xn[2] *= sc; }

    if (h == 0) {
        float4 outv = make_float4(xn[0], xn[1], xn[2], xn[3]);
        x4out[(size_t)n * 4 + q] = outv;
    }
}

extern "C" void kernel_launch(void* const* d_in, const int* in_sizes, int n_in,
                              void* d_out, int out_size, void* d_ws, size_t ws_size,
                              hipStream_t stream) {
    const float* x0    = (const float*)d_in[0];
    const int*   ei    = (const int*)d_in[1];   // (2, NE): row0=src, row1=dst
    const float* W_msg = (const float*)d_in[2];
    const float* b_msg = (const float*)d_in[3];
    const float* W_out = (const float*)d_in[4];
    const float* b_out = (const float*)d_in[5];

    float* X = (float*)d_out;                   // final state buffer (ping-pong B1)

    // ws layout: Y (NN*16 f), cnt (NN), offs (NN+1), bsum (NSB), csr (NE), Wc, bc
    float* Y    = (float*)d_ws;                 // ping-pong B0, 6.4 MB
    int*   cnt  = (int*)(Y + (size_t)NN * IN_DIM);
    int*   offs = cnt + NN;
    int*   bsum = offs + NN + 1;
    int*   csr  = bsum + NSB + 1;
    float* Wc   = (float*)(csr + NE);
    float* bc   = Wc + 256;

    const int* src = ei;
    const int* dst = ei + NE;

    compute_wc_kernel<<<1, 256, 0, stream>>>(W_msg, b_msg, W_out, Wc, bc);
    hipMemsetAsync(cnt, 0, (size_t)NN * sizeof(int), stream);
    hist_kernel<<<(NE + 255) / 256, 256, 0, stream>>>(dst, cnt);
    scan1_kernel<<<NSB, 256, 0, stream>>>(cnt, offs, bsum);
    scan2_kernel<<<1, 512, 0, stream>>>(bsum, offs);
    scan3_kernel<<<NSB, 256, 0, stream>>>(bsum, offs);
    fill_oct_kernel<<<NCHUNK * NOCT, 256, 0, stream>>>(src, dst, offs, cnt, csr);

    const int step_threads = NN * 8;
    const int step_blocks = (step_threads + 255) / 256;

    // 4 steps, ping-pong: x0 -> Y -> X -> Y -> X (final lands in d_out)
    const float* bufs_in[4]  = { x0, Y, X, Y };
    float*       bufs_out[4] = { Y,  X, Y, X };
    for (int s = 0; s < 4; ++s) {
        step_kernel<<<step_blocks, 256, 0, stream>>>(
            (const float4*)bufs_in[s], offs, csr, Wc, bc, b_out,
            (float4*)bufs_out[s]);
    }
}